// Round 2
// baseline (247.175 us; speedup 1.0000x reference)
//
#include <hip/hip_runtime.h>

// Problem constants (from reference): N=64, A=5, C=20, FM=52, M=32
#define N_IMG 64
#define NA 5
#define NC 20
#define FM 52
#define NM 32
#define FMFM (FM * FM)                 // 2704
#define CELLS_PER_IMG (NA * FMFM)      // 13520
#define BLOCK 256
#define BLOCKS_PER_IMG ((CELLS_PER_IMG + BLOCK - 1) / BLOCK)  // 53

__device__ __forceinline__ float smooth_l1(float a, float b) {
    float d = a - b;
    float ad = fabsf(d);
    return ad < 1.0f ? 0.5f * d * d : ad - 0.5f;
}

__global__ __launch_bounds__(BLOCK) void yolo_loss_main(
    const float* __restrict__ preds,     // [N, A*25, FM, FM]
    const float* __restrict__ loc_t,     // [N, A, 4, FM, FM]
    const float* __restrict__ cls_t,     // [N, A, C, FM, FM]
    const float* __restrict__ box_t,     // [N, M, 4] xyxy
    const float* __restrict__ anchors,   // [A, 2]
    double* __restrict__ acc)            // acc[0]=loss sum, acc[1]=num_pos
{
    __shared__ float sbox[NM * 4];
    __shared__ float sarea[NM];
    __shared__ double wsum[BLOCK / 64];
    __shared__ double wpos[BLOCK / 64];

    const int n = blockIdx.y;
    const int tid = threadIdx.x;

    // Stage this image's target boxes + their areas in LDS.
    if (tid < NM * 4) sbox[tid] = box_t[n * NM * 4 + tid];
    __syncthreads();
    if (tid < NM) {
        float x1 = sbox[tid * 4 + 0], y1 = sbox[tid * 4 + 1];
        float x2 = sbox[tid * 4 + 2], y2 = sbox[tid * 4 + 3];
        sarea[tid] = (x2 - x1) * (y2 - y1);
    }
    __syncthreads();

    const int cell = blockIdx.x * BLOCK + tid;
    float loss = 0.0f;
    float posf = 0.0f;

    if (cell < CELLS_PER_IMG) {
        const int a = cell / FMFM;
        const int rem = cell - a * FMFM;   // y*FM + x
        const int y = rem / FM;
        const int x = rem - y * FM;

        // 25 pred channels for this (n, a, y, x); lane-coalesced per channel.
        const float* pbase = preds + (size_t)(n * NA + a) * 25 * FMFM + rem;
        float p[25];
        #pragma unroll
        for (int ch = 0; ch < 25; ++ch) p[ch] = pbase[ch * FMFM];

        // Class targets + positivity.
        const float* cbase = cls_t + (size_t)(n * NA + a) * NC * FMFM + rem;
        float ct[NC];
        float cmax = 0.0f;
        #pragma unroll
        for (int c = 0; c < NC; ++c) { ct[c] = cbase[c * FMFM]; cmax = fmaxf(cmax, ct[c]); }
        const bool pos = cmax > 0.0f;
        posf = pos ? 1.0f : 0.0f;

        // Loc predictions.
        float sx = 1.0f / (1.0f + expf(-p[0]));
        float sy = 1.0f / (1.0f + expf(-p[1]));
        float ew = expf(p[2]);
        float eh = expf(p[3]);

        // Loc loss (masked by pos; mask multiplies the smooth_l1 result).
        if (pos) {
            const float* lbase = loc_t + (size_t)(n * NA + a) * 4 * FMFM + rem;
            loss += smooth_l1(sx, lbase[0 * FMFM]);
            loss += smooth_l1(sy, lbase[1 * FMFM]);
            loss += smooth_l1(ew, lbase[2 * FMFM]);
            loss += smooth_l1(eh, lbase[3 * FMFM]);
        }

        // Decode box: center = sigmoid(xy) + (x, y) grid offset; wh = anchor * exp(wh).
        float aw = anchors[a * 2 + 0], ah = anchors[a * 2 + 1];
        float bx = sx + (float)x;
        float by = sy + (float)y;
        float bw = aw * ew, bh = ah * eh;
        float px1 = bx - 0.5f * bw, py1 = by - 0.5f * bh;
        float px2 = bx + 0.5f * bw, py2 = by + 0.5f * bh;
        float area_p = (px2 - px1) * (py2 - py1);

        // Max IoU over the M=32 target boxes.
        float best = -1e30f;
        #pragma unroll 8
        for (int t = 0; t < NM; ++t) {
            float lx = fmaxf(px1, sbox[t * 4 + 0]);
            float ly = fmaxf(py1, sbox[t * 4 + 1]);
            float rx = fminf(px2, sbox[t * 4 + 2]);
            float ry = fminf(py2, sbox[t * 4 + 3]);
            float w = fmaxf(rx - lx, 0.0f);
            float h = fmaxf(ry - ly, 0.0f);
            float inter = w * h;
            float iou = inter / (area_p + sarea[t] - inter);
            best = fmaxf(best, iou);
        }

        // IoU loss: mask applied INSIDE smooth_l1, summed over all cells.
        float iou_pred = 1.0f / (1.0f + expf(-p[4]));
        float mask = pos ? 1.0f : 0.1f;
        loss += smooth_l1(iou_pred * mask, best * mask);

        // Class softmax over C=20 with max subtraction, then masked smooth_l1.
        float m = p[5];
        #pragma unroll
        for (int c = 1; c < NC; ++c) m = fmaxf(m, p[5 + c]);
        float e[NC];
        float s = 0.0f;
        #pragma unroll
        for (int c = 0; c < NC; ++c) { e[c] = expf(p[5 + c] - m); s += e[c]; }
        float inv = 1.0f / s;
        #pragma unroll
        for (int c = 0; c < NC; ++c) {
            if (ct[c] > 0.0f) loss += smooth_l1(e[c] * inv, ct[c]);
        }
    }

    // Reduction: wave shfl in double -> cross-wave LDS -> one atomic per block.
    double dl = (double)loss;
    double dp = (double)posf;
    #pragma unroll
    for (int off = 32; off > 0; off >>= 1) {
        dl += __shfl_down(dl, off);
        dp += __shfl_down(dp, off);
    }
    const int wave = tid >> 6, lane = tid & 63;
    if (lane == 0) { wsum[wave] = dl; wpos[wave] = dp; }
    __syncthreads();
    if (tid == 0) {
        double tl = 0.0, tp = 0.0;
        #pragma unroll
        for (int w = 0; w < BLOCK / 64; ++w) { tl += wsum[w]; tp += wpos[w]; }
        atomicAdd(&acc[0], tl);
        atomicAdd(&acc[1], tp);
    }
}

__global__ void yolo_loss_finalize(const double* __restrict__ acc,
                                   float* __restrict__ out) {
    out[0] = (float)(acc[0] / acc[1]);
}

extern "C" void kernel_launch(void* const* d_in, const int* in_sizes, int n_in,
                              void* d_out, int out_size, void* d_ws, size_t ws_size,
                              hipStream_t stream) {
    const float* preds   = (const float*)d_in[0];
    const float* loc_t   = (const float*)d_in[1];
    const float* cls_t   = (const float*)d_in[2];
    const float* box_t   = (const float*)d_in[3];
    const float* anchors = (const float*)d_in[4];
    double* acc = (double*)d_ws;

    // d_ws is re-poisoned to 0xAA before every call — zero the accumulators.
    hipMemsetAsync(d_ws, 0, 2 * sizeof(double), stream);

    dim3 grid(BLOCKS_PER_IMG, N_IMG);
    yolo_loss_main<<<grid, BLOCK, 0, stream>>>(preds, loc_t, cls_t, box_t,
                                               anchors, acc);
    yolo_loss_finalize<<<1, 1, 0, stream>>>(acc, (float*)d_out);
}